// Round 1
// baseline (95.098 us; speedup 1.0000x reference)
//
#include <hip/hip_runtime.h>
#include <math.h>

namespace {

constexpr int   kB     = 64;
constexpr int   kA     = 3;
constexpr int   kC     = 20;
constexpr int   kG     = 76;
constexpr int   kGG    = kG * kG;              // 5776
constexpr int   kCH    = 5 + kC;               // 25
constexpr int   kNCell = kB * kA * kGG;        // 1,108,992
constexpr int   kNC4   = kNCell / 4;           // 277,248
constexpr int   kBlock = 256;
constexpr int   kGrid  = (kNC4 + kBlock - 1) / kBlock;  // 1083 (exact)
constexpr float kEps   = 1e-7f;
constexpr float kInvG  = 1.0f / (float)kG;

__device__ __forceinline__ float softplusf(float x) {
  // log(1 + exp(x)), stable
  return fmaxf(x, 0.0f) + log1pf(__expf(-fabsf(x)));
}
__device__ __forceinline__ float sigmoidf(float x) {
  return 1.0f / (1.0f + __expf(-x));
}
__device__ __forceinline__ float clamp01(float x) {
  return fminf(fmaxf(x, 0.0f), 1.0f);
}

__device__ __forceinline__ float ciou_loss(
    float x1p, float y1p, float x2p, float y2p,
    float x1t, float y1t, float x2t, float y2t) {
  float iw     = fmaxf(fminf(x2p, x2t) - fmaxf(x1p, x1t), 0.0f);
  float ih     = fmaxf(fminf(y2p, y2t) - fmaxf(y1p, y1t), 0.0f);
  float inter  = iw * ih;
  float area_p = fmaxf(x2p - x1p, 0.0f) * fmaxf(y2p - y1p, 0.0f);
  float area_t = fmaxf(x2t - x1t, 0.0f) * fmaxf(y2t - y1t, 0.0f);
  float uni    = area_p + area_t - inter + kEps;
  float iou    = inter / uni;
  float dx     = (x1p + x2p - x1t - x2t) * 0.5f;
  float dy     = (y1p + y2p - y1t - y2t) * 0.5f;
  float rho2   = dx * dx + dy * dy;
  float enw    = fmaxf(fmaxf(x2p, x2t) - fminf(x1p, x1t), kEps);
  float enh    = fmaxf(fmaxf(y2p, y2t) - fminf(y1p, y1t), kEps);
  float c2     = enw * enw + enh * enh;
  float wp     = fmaxf(x2p - x1p, kEps);
  float hp     = fmaxf(y2p - y1p, kEps);
  float wt     = fmaxf(x2t - x1t, kEps);
  float ht     = fmaxf(y2t - y1t, kEps);
  const float k4pi2 = 4.0f / (float)(M_PI * M_PI);
  float dat  = atanf(wt / ht) - atanf(wp / hp);
  float v    = k4pi2 * dat * dat;
  float alpha = v / (1.0f - iou + v + kEps);
  float ciou = iou - rho2 / (c2 + kEps) - alpha * v;
  return 1.0f - ciou;
}

// Reduce 5 per-thread values across the block; lane pattern is fixed ->
// deterministic. Result written by thread 0.
__device__ __forceinline__ void block_reduce5(float r[5], float* out) {
  #pragma unroll
  for (int off = 32; off > 0; off >>= 1) {
    #pragma unroll
    for (int s = 0; s < 5; ++s) r[s] += __shfl_down(r[s], off, 64);
  }
  __shared__ float red[kBlock / 64][5];
  const int lane = threadIdx.x & 63;
  const int wid  = threadIdx.x >> 6;
  if (lane == 0) {
    #pragma unroll
    for (int s = 0; s < 5; ++s) red[wid][s] = r[s];
  }
  __syncthreads();
  if (threadIdx.x == 0) {
    float acc[5];
    #pragma unroll
    for (int s = 0; s < 5; ++s) acc[s] = red[0][s];
    #pragma unroll
    for (int w = 1; w < kBlock / 64; ++w)
      #pragma unroll
      for (int s = 0; s < 5; ++s) acc[s] += red[w][s];
    #pragma unroll
    for (int s = 0; s < 5; ++s) out[s] = acc[s];
  }
}

__global__ __launch_bounds__(kBlock) void yolo_cell_kernel(
    const float* __restrict__ preds,
    const float* __restrict__ tgts,
    const float* __restrict__ anchors,
    float* __restrict__ partials) {
  const int q = blockIdx.x * kBlock + threadIdx.x;  // grid is exact (kNC4 = kGrid*kBlock)

  float s[5] = {0.f, 0.f, 0.f, 0.f, 0.f};  // n_obj, coord, objconf, noobj, cls

  const int cell = q * 4;
  const int ba   = cell / kGG;        // (b*A + a); 4 cells share it (kGG % 4 == 0)
  const int j0   = cell - ba * kGG;   // plane index of cell 0, multiple of 4
  const int a    = ba % kA;
  const float aw = anchors[2 * a]     * kInvG;
  const float ah = anchors[2 * a + 1] * kInvG;

  const float* pb = preds + (size_t)ba * kCH * kGG + j0;

  // targets: 4 cells * 5 floats = 5 aligned float4
  union { float4 v[5]; float f[20]; } T;
  const float4* tb = (const float4*)(tgts + (size_t)cell * 5);
  #pragma unroll
  for (int i = 0; i < 5; ++i) T.v[i] = tb[i];

  // box channels 0..4 for the 4 cells
  float4 P0 = *(const float4*)(pb + 0 * kGG);
  float4 P1 = *(const float4*)(pb + 1 * kGG);
  float4 P2 = *(const float4*)(pb + 2 * kGG);
  float4 P3 = *(const float4*)(pb + 3 * kGG);
  float4 P4 = *(const float4*)(pb + 4 * kGG);
  const float p0a[4] = {P0.x, P0.y, P0.z, P0.w};
  const float p1a[4] = {P1.x, P1.y, P1.z, P1.w};
  const float p2a[4] = {P2.x, P2.y, P2.z, P2.w};
  const float p3a[4] = {P3.x, P3.y, P3.z, P3.w};
  const float p4a[4] = {P4.x, P4.y, P4.z, P4.w};

  float mask[4];

  #pragma unroll
  for (int i = 0; i < 4; ++i) {
    const int j  = j0 + i;
    const int gy = j / kG;
    const int gx = j - gy * kG;
    const float fgx = (float)gx, fgy = (float)gy;

    const float tx = T.f[i * 5 + 0];
    const float ty = T.f[i * 5 + 1];
    const float tw = T.f[i * 5 + 2];
    const float th = T.f[i * 5 + 3];
    const float tc = T.f[i * 5 + 4];
    const bool obj = tc > 0.0f;
    const float m  = obj ? 1.0f : 0.0f;
    mask[i] = m;
    s[0] += m;

    // conf BCE: softplus(x) - t*x for obj; noobj: -log1p(-sigmoid(x)) = softplus(x)
    const float sp4 = softplusf(p4a[i]);
    s[3] += obj ? 0.0f : sp4;
    s[2] += obj ? (sp4 - tc * p4a[i]) : 0.0f;

    // boxes (computed branchlessly; all denominators are +eps-guarded)
    const float sx  = sigmoidf(p0a[i]);
    const float sy  = sigmoidf(p1a[i]);
    const float pcx = (fgx + sx) * kInvG;
    const float pcy = (fgy + sy) * kInvG;
    const float pw  = __expf(p2a[i]) * aw;
    const float ph  = __expf(p3a[i]) * ah;
    const float x1p = clamp01(pcx - 0.5f * pw);
    const float y1p = clamp01(pcy - 0.5f * ph);
    const float x2p = clamp01(pcx + 0.5f * pw);
    const float y2p = clamp01(pcy + 0.5f * ph);

    const float tcx = (fgx + tx) * kInvG;
    const float tcy = (fgy + ty) * kInvG;
    const float twv = __expf(tw) * aw;
    const float thv = __expf(th) * ah;
    const float x1t = clamp01(tcx - 0.5f * twv);
    const float y1t = clamp01(tcy - 0.5f * thv);
    const float x2t = clamp01(tcx + 0.5f * twv);
    const float y2t = clamp01(tcy + 0.5f * thv);

    const float cl = ciou_loss(x1p, y1p, x2p, y2p, x1t, y1t, x2t, y2t);
    s[1] += obj ? cl : 0.0f;
  }

  // class channels: -log(sigmoid(x)) = softplus(-x), only obj cells count
  float clsacc = 0.0f;
  #pragma unroll
  for (int c = 0; c < kC; ++c) {
    const float4 pc = *(const float4*)(pb + (size_t)(5 + c) * kGG);
    clsacc += mask[0] * softplusf(-pc.x);
    clsacc += mask[1] * softplusf(-pc.y);
    clsacc += mask[2] * softplusf(-pc.z);
    clsacc += mask[3] * softplusf(-pc.w);
  }
  s[4] = clsacc;

  block_reduce5(s, partials + (size_t)blockIdx.x * 5);
}

__global__ __launch_bounds__(256) void yolo_finish_kernel(
    const float* __restrict__ partials, float* __restrict__ out) {
  float r[5] = {0.f, 0.f, 0.f, 0.f, 0.f};
  for (int i = threadIdx.x; i < kGrid; i += 256) {
    #pragma unroll
    for (int s = 0; s < 5; ++s) r[s] += partials[(size_t)i * 5 + s];
  }
  __shared__ float outbuf[5];
  block_reduce5(r, outbuf);
  __syncthreads();
  if (threadIdx.x == 0) {
    const float n_obj   = outbuf[0];
    const float coord   = outbuf[1];
    const float objc    = outbuf[2];
    const float noobj   = outbuf[3];
    const float cls     = outbuf[4];
    const float n_noobj = (float)kNCell - n_obj;

    const float coord_loss = (n_obj > 0.f)   ? coord / fmaxf(n_obj, 1.f)   : 0.f;
    const float obj_loss   = (n_obj > 0.f)   ? objc  / fmaxf(n_obj, 1.f)   : 0.f;
    const float noobj_loss = (n_noobj > 0.f) ? noobj / fmaxf(n_noobj, 1.f) : 0.f;
    const float class_loss = (n_obj > 0.f)   ? cls / fmaxf(n_obj * (float)kC, 1.f) : 0.f;

    out[0] = 10.0f * coord_loss + 1.0f * obj_loss + 0.5f * noobj_loss + class_loss;
  }
}

}  // namespace

extern "C" void kernel_launch(void* const* d_in, const int* in_sizes, int n_in,
                              void* d_out, int out_size, void* d_ws, size_t ws_size,
                              hipStream_t stream) {
  const float* preds   = (const float*)d_in[0];
  const float* tgts    = (const float*)d_in[1];
  const float* anchors = (const float*)d_in[2];
  float* out      = (float*)d_out;
  float* partials = (float*)d_ws;  // kGrid * 5 floats ~ 22 KB

  yolo_cell_kernel<<<kGrid, kBlock, 0, stream>>>(preds, tgts, anchors, partials);
  yolo_finish_kernel<<<1, 256, 0, stream>>>(partials, out);
}